// Round 8
// baseline (26683.908 us; speedup 1.0000x reference)
//
#include <hip/hip_runtime.h>
#include <math.h>

#define S_LEN 2048
#define HD 512
#define G4 2048      // 4*HD gate rows
#define E_DIM 512
#define NTAG 12
#define TAG_START 10
#define TAG_STOP 11
#define NEGV -10000.0f

#define NBW 64            // blocks per direction
#define CTR_STRIDE 32     // uints per counter (128B line padding)

// ---------------- X pre-GEMM: X[dir][t][row] = emb[t].Wih[row] + bih[row]+bhh[row] ----------------
#define BK 16
__global__ __launch_bounds__(256) void xgemm_k(
    const int* __restrict__ sent, const float* __restrict__ embed,
    const float* __restrict__ WihF, const float* __restrict__ WihB,
    const float* __restrict__ bihF, const float* __restrict__ bhhF,
    const float* __restrict__ bihB, const float* __restrict__ bhhB,
    float* __restrict__ Xf, float* __restrict__ Xb)
{
    const int dir = blockIdx.z;
    const float* __restrict__ Wih = dir ? WihB : WihF;
    const float* __restrict__ bih = dir ? bihB : bihF;
    const float* __restrict__ bhh = dir ? bhhB : bhhF;
    float* __restrict__ X = dir ? Xb : Xf;

    const int m0 = blockIdx.y * 64;   // t tile
    const int n0 = blockIdx.x * 64;   // gate-row tile
    const int tid = threadIdx.x;

    __shared__ float At[BK][68];      // transposed tiles: [k][row], pad 68
    __shared__ float Bt[BK][68];

    const int lr = tid >> 2;          // 0..63 staging row
    const int lc = (tid & 3) * 4;     // k sub-offset
    const float* __restrict__ arow = embed + (size_t)sent[m0 + lr] * E_DIM + lc;
    const float* __restrict__ brow = Wih + (size_t)(n0 + lr) * E_DIM + lc;

    const int tx = tid & 15, ty = tid >> 4;
    float acc[4][4] = {};

    for (int kt = 0; kt < E_DIM; kt += BK) {
        const float4 av = *(const float4*)(arow + kt);
        const float4 bv = *(const float4*)(brow + kt);
        __syncthreads();
        At[lc+0][lr] = av.x; At[lc+1][lr] = av.y; At[lc+2][lr] = av.z; At[lc+3][lr] = av.w;
        Bt[lc+0][lr] = bv.x; Bt[lc+1][lr] = bv.y; Bt[lc+2][lr] = bv.z; Bt[lc+3][lr] = bv.w;
        __syncthreads();
        #pragma unroll
        for (int kk = 0; kk < BK; ++kk) {
            const float4 a4 = *(const float4*)&At[kk][ty*4];
            const float4 b4 = *(const float4*)&Bt[kk][tx*4];
            const float a_[4] = {a4.x, a4.y, a4.z, a4.w};
            const float b_[4] = {b4.x, b4.y, b4.z, b4.w};
            #pragma unroll
            for (int i = 0; i < 4; ++i)
                #pragma unroll
                for (int j = 0; j < 4; ++j)
                    acc[i][j] += a_[i] * b_[j];
        }
    }
    float bias[4];
    #pragma unroll
    for (int j = 0; j < 4; ++j) {
        int col = n0 + tx*4 + j;
        bias[j] = bih[col] + bhh[col];
    }
    #pragma unroll
    for (int i = 0; i < 4; ++i) {
        int t = m0 + ty*4 + i;
        float4 o;
        o.x = acc[i][0] + bias[0];
        o.y = acc[i][1] + bias[1];
        o.z = acc[i][2] + bias[2];
        o.w = acc[i][3] + bias[3];
        *(float4*)(X + (size_t)t * G4 + n0 + tx*4) = o;
    }
}

// ---------------- recurrence: r1 structure + counter-based readiness ----------------
// Producers: h stores (agent atomics) -> vmcnt(0) -> barrier -> ONE fetch_add(RELEASE)/block.
// Consumers: poll ONE counter line (1 lane/wave, s_sleep backoff), then one-shot row read.
__global__ __attribute__((amdgpu_flat_work_group_size(256, 256), amdgpu_waves_per_eu(1, 1)))
void lstm_rec(
    const float* __restrict__ WhhF, const float* __restrict__ WhhB,
    const float* __restrict__ Xf, const float* __restrict__ Xb,
    const float* __restrict__ h0, const float* __restrict__ c0,
    unsigned* __restrict__ hfp, unsigned* __restrict__ hbp,
    unsigned* __restrict__ ctr)     // [2][S_LEN][CTR_STRIDE]
{
    const int bid = blockIdx.x;
    const int dir = bid >> 6;          // 0 fwd, 1 bwd
    const int b   = bid & 63;
    const float* __restrict__ Whh = dir ? WhhB : WhhF;
    const float* __restrict__ X   = dir ? Xb : Xf;
    unsigned* __restrict__ Hu = dir ? hbp : hfp;
    unsigned* __restrict__ cbase = ctr + (size_t)dir * S_LEN * CTR_STRIDE;

    const int tid = threadIdx.x;
    const int r = tid >> 3;            // 0..31 local gate-row
    const int k = tid & 7;             // column chunk
    const int ul = r >> 2;             // 0..7 local unit
    const int g = r & 3;               // gate (i,f,g,o)
    const int unit = b * 8 + ul;
    const int row_g = g * HD + unit;   // global gate row in [0,2048)

    // 64 weights per thread as 16 NAMED float4s, pinned opaque (r3-proven: VGPR~132, no spill)
    const float4* wp = (const float4*)(Whh + (size_t)row_g * HD + k * 64);
#define WDECL(i) float4 w##i = wp[i];
    WDECL(0)  WDECL(1)  WDECL(2)  WDECL(3)
    WDECL(4)  WDECL(5)  WDECL(6)  WDECL(7)
    WDECL(8)  WDECL(9)  WDECL(10) WDECL(11)
    WDECL(12) WDECL(13) WDECL(14) WDECL(15)
#define WPIN(i) asm volatile("" : "+v"(w##i.x), "+v"(w##i.y), "+v"(w##i.z), "+v"(w##i.w));
    WPIN(0)  WPIN(1)  WPIN(2)  WPIN(3)
    WPIN(4)  WPIN(5)  WPIN(6)  WPIN(7)
    WPIN(8)  WPIN(9)  WPIN(10) WPIN(11)
    WPIN(12) WPIN(13) WPIN(14) WPIN(15)

    __shared__ float hlds[2][8 * 68];  // double-buffered, stride 68 (bank-conflict-free, r1-proven)

    const int l  = tid & 63;
    const int l0 = l & 32;
    const bool cellln = (l & 31) == 0;
    float c = cellln ? c0[dir*HD + unit] : 0.f;

    float xval = 0.f;
    if (k == 0) xval = X[(size_t)(dir ? (S_LEN-1) : 0) * G4 + row_g];

    for (int s = 0; s < S_LEN; ++s) {
        const int t_io = dir ? (S_LEN-1-s) : s;
        float* __restrict__ hl = hlds[s & 1];

        if (s == 0) {
            float2 hv = *(const float2*)(h0 + dir*HD + tid*2);
            int ch = tid >> 5, off = (tid*2) & 63;
            hl[ch*68 + off]   = hv.x;
            hl[ch*68 + off+1] = hv.y;
        } else {
            const int prev = dir ? (t_io+1) : (t_io-1);
            // 1 lane per wave polls the step counter (own 128B line); others wait at reconverge
            if (l == 0) {
                const unsigned* cp = cbase + (size_t)prev * CTR_STRIDE;
                unsigned v; int it = 0;
                do {
                    v = __hip_atomic_load(cp, __ATOMIC_ACQUIRE, __HIP_MEMORY_SCOPE_AGENT);
                    if (v >= NBW) break;
                    __builtin_amdgcn_s_sleep(1);
                } while (++it < (1 << 16));   // bounded escape -> visible failure, never hangs
            }
            // one-shot row read: 256 lanes x 8B, no re-poll
            const unsigned long long* src =
                (const unsigned long long*)(Hu + (size_t)prev*HD) + tid;
            const unsigned long long v =
                __hip_atomic_load(src, __ATOMIC_RELAXED, __HIP_MEMORY_SCOPE_AGENT);
            int ch = tid >> 5, off = (tid*2) & 63;
            hl[ch*68 + off]   = __uint_as_float((unsigned)v);
            hl[ch*68 + off+1] = __uint_as_float((unsigned)(v >> 32));
        }
        __syncthreads();

        // prefetch next step's X (hides under dot)
        float xnext = 0.f;
        if (k == 0 && s + 1 < S_LEN) {
            const int t_nx = dir ? (t_io-1) : (t_io+1);
            xnext = X[(size_t)t_nx * G4 + row_g];
        }

        // 64-wide dot chunk (h broadcast from LDS, conflict-free)
        float a0 = 0.f, a1 = 0.f, a2 = 0.f, a3 = 0.f;
        const float* __restrict__ hp = &hl[k * 68];
#define WDOT(i) { const float4 hv = *(const float4*)(hp + 4*(i)); \
        a0 += w##i.x*hv.x; a1 += w##i.y*hv.y; a2 += w##i.z*hv.z; a3 += w##i.w*hv.w; }
        WDOT(0)  WDOT(1)  WDOT(2)  WDOT(3)
        WDOT(4)  WDOT(5)  WDOT(6)  WDOT(7)
        WDOT(8)  WDOT(9)  WDOT(10) WDOT(11)
        WDOT(12) WDOT(13) WDOT(14) WDOT(15)
        float acc = (a0 + a1) + (a2 + a3);

        acc += __shfl_xor(acc, 1);
        acc += __shfl_xor(acc, 2);
        acc += __shfl_xor(acc, 4);
        const float pre = acc + xval;          // valid at k==0 lanes

        const float yy  = (g == 2) ? 2.f*pre : pre;
        const float sg  = 1.f / (1.f + __expf(-yy));
        const float act = (g == 2) ? 2.f*sg - 1.f : sg;

        const float a_i = __shfl(act, l0 + 0);
        const float a_f = __shfl(act, l0 + 8);
        const float a_g = __shfl(act, l0 + 16);
        const float a_o = __shfl(act, l0 + 24);

        float hval = 0.f;
        if (cellln) {
            c = a_f*c + a_i*a_g;
            const float th = 2.f / (1.f + __expf(-2.f*c)) - 1.f;
            hval = a_o * th;
        }
        // pair the two units of this wave into one 8B agent-scope store (lane 0 of wave)
        const float h_hi = __shfl(hval, 32);
        if (l == 0) {
            const unsigned long long pv =
                (unsigned long long)__float_as_uint(hval) |
                ((unsigned long long)__float_as_uint(h_hi) << 32);
            unsigned long long* dst =
                (unsigned long long*)(Hu + (size_t)t_io*HD) + (unit >> 1);
            __hip_atomic_store(dst, pv, __ATOMIC_RELAXED, __HIP_MEMORY_SCOPE_AGENT);
        }
        // release: drain this wave's stores, sync waves, one counter add per block
        asm volatile("s_waitcnt vmcnt(0)" ::: "memory");
        __syncthreads();
        if (tid == 0)
            __hip_atomic_fetch_add(cbase + (size_t)t_io * CTR_STRIDE, 1u,
                                   __ATOMIC_RELEASE, __HIP_MEMORY_SCOPE_AGENT);
        xval = xnext;
    }
}

// ---------------- feats: [hf,hb] @ Wout.T + bout ----------------
__global__ __launch_bounds__(256) void feats_k(
    const float* __restrict__ hf, const float* __restrict__ hb,
    const float* __restrict__ Wout, const float* __restrict__ bout,
    float* __restrict__ feats)
{
    int idx = blockIdx.x * blockDim.x + threadIdx.x;
    if (idx >= S_LEN * NTAG) return;
    int t = idx / NTAG, tag = idx - t*NTAG;
    const float* __restrict__ wf  = Wout + (size_t)tag * (2*HD);
    const float* __restrict__ ha  = hf + (size_t)t * HD;
    const float* __restrict__ hbr = hb + (size_t)t * HD;
    float a0=0.f, a1=0.f, a2=0.f, a3=0.f;
    for (int i = 0; i < HD; i += 4) {
        float4 h4 = *(const float4*)(ha + i);
        float4 w4 = *(const float4*)(wf + i);
        a0 += h4.x*w4.x; a1 += h4.y*w4.y; a2 += h4.z*w4.z; a3 += h4.w*w4.w;
    }
    for (int i = 0; i < HD; i += 4) {
        float4 h4 = *(const float4*)(hbr + i);
        float4 w4 = *(const float4*)(wf + HD + i);
        a0 += h4.x*w4.x; a1 += h4.y*w4.y; a2 += h4.z*w4.z; a3 += h4.w*w4.w;
    }
    feats[idx] = a0+a1+a2+a3 + bout[tag];
}

// ---------------- Viterbi forward + backtrace, single block ----------------
__global__ __launch_bounds__(256, 1) void viterbi_k(
    const float* __restrict__ feats, const float* __restrict__ trans,
    float* __restrict__ out)
{
    __shared__ float fl[S_LEN * NTAG];           // 96 KB
    __shared__ unsigned char bpl[S_LEN * NTAG];  // 24 KB
    {
        const float4* src = (const float4*)feats;
        float4* dst = (float4*)fl;
        for (int i = threadIdx.x; i < S_LEN*NTAG/4; i += 256) dst[i] = src[i];
    }
    __syncthreads();
    if (threadIdx.x < 64) {
        const int ln = threadIdx.x;
        if (ln < NTAG) {
            float tr[NTAG];
            #pragma unroll
            for (int p = 0; p < NTAG; ++p) tr[p] = trans[ln*NTAG + p];
            float fv = (ln == TAG_START) ? 0.f : NEGV;
            for (int t = 0; t < S_LEN; ++t) {
                float best = -3.4e38f; int arg = 0;
                #pragma unroll
                for (int p = 0; p < NTAG; ++p) {
                    float sc = __shfl(fv, p) + tr[p];
                    if (sc > best) { best = sc; arg = p; }   // strict > = first-max (np argmax)
                }
                bpl[t*NTAG + ln] = (unsigned char)arg;
                fv = best + fl[t*NTAG + ln];
            }
            float tsc = fv + trans[TAG_STOP*NTAG + ln];
            float bestt = -3.4e38f; int argt = 0;
            #pragma unroll
            for (int p = 0; p < NTAG; ++p) {
                float v = __shfl(tsc, p);
                if (v > bestt) { bestt = v; argt = p; }
            }
            if (ln == 0) {
                out[0] = bestt;
                int tag = argt;
                for (int t = S_LEN-1; t >= 0; --t) {
                    out[1+t] = (float)tag;
                    tag = bpl[t*NTAG + tag];
                }
            }
        }
    }
}

// ---------------- launch ----------------
extern "C" void kernel_launch(void* const* d_in, const int* in_sizes, int n_in,
                              void* d_out, int out_size, void* d_ws, size_t ws_size,
                              hipStream_t stream)
{
    const int*   sent  = (const int*)d_in[0];
    const float* embed = (const float*)d_in[1];
    const float* WihF  = (const float*)d_in[2];
    const float* WhhF  = (const float*)d_in[3];
    const float* bihF  = (const float*)d_in[4];
    const float* bhhF  = (const float*)d_in[5];
    const float* WihB  = (const float*)d_in[6];
    const float* WhhB  = (const float*)d_in[7];
    const float* bihB  = (const float*)d_in[8];
    const float* bhhB  = (const float*)d_in[9];
    const float* h0    = (const float*)d_in[10];
    const float* c0    = (const float*)d_in[11];
    const float* Wout  = (const float*)d_in[12];
    const float* bout  = (const float*)d_in[13];
    const float* trans = (const float*)d_in[14];
    float* out = (float*)d_out;

    float* ws = (float*)d_ws;
    float* Xf = ws;                                   // 16 MB
    float* Xb = Xf + (size_t)S_LEN * G4;              // 16 MB
    float* hf = Xb + (size_t)S_LEN * G4;              // 4 MB
    float* hb = hf + (size_t)S_LEN * HD;              // 4 MB
    float* feats = hb + (size_t)S_LEN * HD;           // 96 KB
    unsigned* ctr = (unsigned*)(feats + (size_t)S_LEN * NTAG);  // 512 KB counters

    // 1) zero the step counters (readiness is counter-based; h needs no sentinel)
    hipMemsetAsync(ctr, 0, (size_t)2 * S_LEN * CTR_STRIDE * sizeof(unsigned), stream);
    // 2) X pre-GEMM for both directions
    {
        dim3 grid(G4/64, S_LEN/64, 2);
        xgemm_k<<<grid, 256, 0, stream>>>(sent, embed, WihF, WihB,
                                          bihF, bhhF, bihB, bhhB, Xf, Xb);
    }
    // 3) recurrence, both directions concurrently
    lstm_rec<<<2*NBW, 256, 0, stream>>>(WhhF, WhhB, Xf, Xb, h0, c0,
                                        (unsigned*)hf, (unsigned*)hb, ctr);
    // 4) emission features
    {
        int n = S_LEN * NTAG;
        feats_k<<<(n + 255)/256, 256, 0, stream>>>(hf, hb, Wout, bout, feats);
    }
    // 5) Viterbi decode
    viterbi_k<<<1, 256, 0, stream>>>(feats, trans, out);
}

// Round 9
// 4964.232 us; speedup vs baseline: 5.3752x; 5.3752x over previous
//
#include <hip/hip_runtime.h>
#include <math.h>

#define S_LEN 2048
#define HD 512
#define E_DIM 512
#define NTAG 12
#define TAG_START 10
#define TAG_STOP 11
#define NEGV -10000.0f

// byte-repeating sentinel (memset 0x7F) = fp32 3.39e38; |h| < 1 can never equal it
#define SENT 0x7F7F7F7Fu

// ---------------- recurrence: r1 protocol verbatim + fused on-the-fly X ----------------
// 64 blocks/dir x 256 thr. Each block: 8 units (32 gate rows). Whh AND Wih rows pinned in
// VGPRs (r3 mechanism). emb row staged in LDS (double-buffered, prefetched 1 step ahead).
// Sync = r1's proven direct data-poll: relaxed agent atomic 8B loads, unbounded.
__global__ __attribute__((amdgpu_flat_work_group_size(256, 256), amdgpu_waves_per_eu(1, 1)))
void lstm_rec(
    const float* __restrict__ WhhF, const float* __restrict__ WhhB,
    const float* __restrict__ WihF, const float* __restrict__ WihB,
    const float* __restrict__ bihF, const float* __restrict__ bhhF,
    const float* __restrict__ bihB, const float* __restrict__ bhhB,
    const int* __restrict__ sent, const float* __restrict__ embed,
    const float* __restrict__ h0, const float* __restrict__ c0,
    unsigned* __restrict__ hfp, unsigned* __restrict__ hbp)
{
    const int bid = blockIdx.x;
    const int dir = bid >> 6;          // 0 fwd, 1 bwd
    const int b   = bid & 63;
    const float* __restrict__ Whh = dir ? WhhB : WhhF;
    const float* __restrict__ Wih = dir ? WihB : WihF;
    const float* __restrict__ bih = dir ? bihB : bihF;
    const float* __restrict__ bhh = dir ? bhhB : bhhF;
    unsigned* __restrict__ Hu = dir ? hbp : hfp;

    const int tid = threadIdx.x;
    const int r = tid >> 3;            // 0..31 local gate-row
    const int k = tid & 7;             // column chunk
    const int ul = r >> 2;             // 0..7 local unit
    const int g = r & 3;               // gate (i,f,g,o)
    const int unit = b * 8 + ul;
    const int row_g = g * HD + unit;   // global gate row in [0,2048)

    // 64 Whh weights + 64 Wih weights per thread as 32 NAMED float4s, pinned opaque
    const float4* wp = (const float4*)(Whh + (size_t)row_g * HD + k * 64);
    const float4* up = (const float4*)(Wih + (size_t)row_g * E_DIM + k * 64);
#define WDECL(i) float4 w##i = wp[i]; float4 u##i = up[i];
    WDECL(0)  WDECL(1)  WDECL(2)  WDECL(3)
    WDECL(4)  WDECL(5)  WDECL(6)  WDECL(7)
    WDECL(8)  WDECL(9)  WDECL(10) WDECL(11)
    WDECL(12) WDECL(13) WDECL(14) WDECL(15)
#define WPIN(i) asm volatile("" : "+v"(w##i.x), "+v"(w##i.y), "+v"(w##i.z), "+v"(w##i.w), \
                                  "+v"(u##i.x), "+v"(u##i.y), "+v"(u##i.z), "+v"(u##i.w));
    WPIN(0)  WPIN(1)  WPIN(2)  WPIN(3)
    WPIN(4)  WPIN(5)  WPIN(6)  WPIN(7)
    WPIN(8)  WPIN(9)  WPIN(10) WPIN(11)
    WPIN(12) WPIN(13) WPIN(14) WPIN(15)

    __shared__ float hlds[2][8 * 68];  // double-buffered h row, stride 68 (conflict-free)
    __shared__ float elds[2][8 * 68];  // double-buffered emb row, same layout

    const int l  = tid & 63;
    const int l0 = l & 32;
    const bool cellln = (l & 31) == 0;
    float c = cellln ? c0[dir*HD + unit] : 0.f;

    // bias replaces the old X read: constant across steps, added at k==0 lanes
    float xval = 0.f;
    if (k == 0) xval = bih[row_g] + bhh[row_g];

    const int ch  = tid >> 5;          // LDS staging slot
    const int off = (tid * 2) & 63;

    // ---- emb prologue: elds[0] <- row t(0); ereg <- row t(1) ----
    float2 ereg;
    {
        const int t0 = dir ? (S_LEN-1) : 0;
        const float2 ev = ((const float2*)(embed + (size_t)sent[t0] * E_DIM))[tid];
        elds[0][ch*68 + off]   = ev.x;
        elds[0][ch*68 + off+1] = ev.y;
        const int t1 = dir ? (S_LEN-2) : 1;
        ereg = ((const float2*)(embed + (size_t)sent[t1] * E_DIM))[tid];
    }

    for (int s = 0; s < S_LEN; ++s) {
        const int t_io = dir ? (S_LEN-1-s) : s;
        float* __restrict__ hl = hlds[s & 1];

        // write emb row for step s+1 into the other buffer (value prefetched last iter)
        {
            float* __restrict__ el = elds[(s+1) & 1];
            el[ch*68 + off]   = ereg.x;
            el[ch*68 + off+1] = ereg.y;
        }

        if (s == 0) {
            float2 hv = *(const float2*)(h0 + dir*HD + tid*2);
            hl[ch*68 + off]   = hv.x;
            hl[ch*68 + off+1] = hv.y;
        } else {
            const int prev = dir ? (t_io+1) : (t_io-1);
            const unsigned long long* src =
                (const unsigned long long*)(Hu + (size_t)prev*HD) + tid;
            unsigned long long v;
            do {
                v = __hip_atomic_load(src, __ATOMIC_RELAXED, __HIP_MEMORY_SCOPE_AGENT);
            } while ((unsigned)v == SENT || (unsigned)(v >> 32) == SENT);
            hl[ch*68 + off]   = __uint_as_float((unsigned)v);
            hl[ch*68 + off+1] = __uint_as_float((unsigned)(v >> 32));
        }
        __syncthreads();   // single barrier per step (double-buffered hlds/elds)

        // prefetch emb row for step s+2 (consumed at next iteration's top; ~1 step of slack)
        if (s + 2 < S_LEN) {
            const int t2 = dir ? (t_io - 2) : (t_io + 2);
            ereg = ((const float2*)(embed + (size_t)sent[t2] * E_DIM))[tid];
        }

        // 64-wide dot chunk over h (Whh) AND emb (Wih); LDS reads are 8-lane broadcasts
        float a0 = 0.f, a1 = 0.f, a2 = 0.f, a3 = 0.f;
        const float* __restrict__ hp = &hl[k * 68];
        const float* __restrict__ ep = &elds[s & 1][k * 68];
#define WDOT(i) { const float4 hv = *(const float4*)(hp + 4*(i)); \
        a0 += w##i.x*hv.x; a1 += w##i.y*hv.y; a2 += w##i.z*hv.z; a3 += w##i.w*hv.w; } \
        { const float4 ev4 = *(const float4*)(ep + 4*(i)); \
        a0 += u##i.x*ev4.x; a1 += u##i.y*ev4.y; a2 += u##i.z*ev4.z; a3 += u##i.w*ev4.w; }
        WDOT(0)  WDOT(1)  WDOT(2)  WDOT(3)
        WDOT(4)  WDOT(5)  WDOT(6)  WDOT(7)
        WDOT(8)  WDOT(9)  WDOT(10) WDOT(11)
        WDOT(12) WDOT(13) WDOT(14) WDOT(15)
        float acc = (a0 + a1) + (a2 + a3);

        // reduce across the 8 chunk lanes
        acc += __shfl_xor(acc, 1);
        acc += __shfl_xor(acc, 2);
        acc += __shfl_xor(acc, 4);
        const float pre = acc + xval;          // valid at k==0 lanes

        // activation: sigmoid for i,f,o; tanh (=2*sig(2x)-1) for g
        const float yy  = (g == 2) ? 2.f*pre : pre;
        const float sg  = 1.f / (1.f + __expf(-yy));
        const float act = (g == 2) ? 2.f*sg - 1.f : sg;

        const float a_i = __shfl(act, l0 + 0);
        const float a_f = __shfl(act, l0 + 8);
        const float a_g = __shfl(act, l0 + 16);
        const float a_o = __shfl(act, l0 + 24);

        float hval = 0.f;
        if (cellln) {
            c = a_f*c + a_i*a_g;
            const float th = 2.f / (1.f + __expf(-2.f*c)) - 1.f;
            hval = a_o * th;
        }
        // pair the two units of this wave into one 8B agent-scope store (lane 0 of wave)
        const float h_hi = __shfl(hval, l0 ? 96 : 32, 64);
        if (l == 0) {
            const unsigned long long pv =
                (unsigned long long)__float_as_uint(hval) |
                ((unsigned long long)__float_as_uint(h_hi) << 32);
            unsigned long long* dst =
                (unsigned long long*)(Hu + (size_t)t_io*HD) + (unit >> 1);
            __hip_atomic_store(dst, pv, __ATOMIC_RELAXED, __HIP_MEMORY_SCOPE_AGENT);
        }
        __syncthreads();   // protect LDS before next staging (r1 semantics)
    }
}

// ---------------- feats: [hf,hb] @ Wout.T + bout ----------------
__global__ __launch_bounds__(256) void feats_k(
    const float* __restrict__ hf, const float* __restrict__ hb,
    const float* __restrict__ Wout, const float* __restrict__ bout,
    float* __restrict__ feats)
{
    int idx = blockIdx.x * blockDim.x + threadIdx.x;
    if (idx >= S_LEN * NTAG) return;
    int t = idx / NTAG, tag = idx - t*NTAG;
    const float* __restrict__ wf  = Wout + (size_t)tag * (2*HD);
    const float* __restrict__ ha  = hf + (size_t)t * HD;
    const float* __restrict__ hbr = hb + (size_t)t * HD;
    float a0=0.f, a1=0.f, a2=0.f, a3=0.f;
    for (int i = 0; i < HD; i += 4) {
        float4 h4 = *(const float4*)(ha + i);
        float4 w4 = *(const float4*)(wf + i);
        a0 += h4.x*w4.x; a1 += h4.y*w4.y; a2 += h4.z*w4.z; a3 += h4.w*w4.w;
    }
    for (int i = 0; i < HD; i += 4) {
        float4 h4 = *(const float4*)(hbr + i);
        float4 w4 = *(const float4*)(wf + HD + i);
        a0 += h4.x*w4.x; a1 += h4.y*w4.y; a2 += h4.z*w4.z; a3 += h4.w*w4.w;
    }
    feats[idx] = a0+a1+a2+a3 + bout[tag];
}

// ---------------- Viterbi forward + backtrace, single block ----------------
__global__ __launch_bounds__(256, 1) void viterbi_k(
    const float* __restrict__ feats, const float* __restrict__ trans,
    float* __restrict__ out)
{
    __shared__ float fl[S_LEN * NTAG];           // 96 KB
    __shared__ unsigned char bpl[S_LEN * NTAG];  // 24 KB
    {
        const float4* src = (const float4*)feats;
        float4* dst = (float4*)fl;
        for (int i = threadIdx.x; i < S_LEN*NTAG/4; i += 256) dst[i] = src[i];
    }
    __syncthreads();
    if (threadIdx.x < 64) {
        const int ln = threadIdx.x;
        if (ln < NTAG) {
            float tr[NTAG];
            #pragma unroll
            for (int p = 0; p < NTAG; ++p) tr[p] = trans[ln*NTAG + p];
            float fv = (ln == TAG_START) ? 0.f : NEGV;
            for (int t = 0; t < S_LEN; ++t) {
                float best = -3.4e38f; int arg = 0;
                #pragma unroll
                for (int p = 0; p < NTAG; ++p) {
                    float sc = __shfl(fv, p) + tr[p];
                    if (sc > best) { best = sc; arg = p; }   // strict > = first-max (np argmax)
                }
                bpl[t*NTAG + ln] = (unsigned char)arg;
                fv = best + fl[t*NTAG + ln];
            }
            float tsc = fv + trans[TAG_STOP*NTAG + ln];
            float bestt = -3.4e38f; int argt = 0;
            #pragma unroll
            for (int p = 0; p < NTAG; ++p) {
                float v = __shfl(tsc, p);
                if (v > bestt) { bestt = v; argt = p; }
            }
            if (ln == 0) {
                out[0] = bestt;
                int tag = argt;
                for (int t = S_LEN-1; t >= 0; --t) {
                    out[1+t] = (float)tag;
                    tag = bpl[t*NTAG + tag];
                }
            }
        }
    }
}

// ---------------- launch ----------------
extern "C" void kernel_launch(void* const* d_in, const int* in_sizes, int n_in,
                              void* d_out, int out_size, void* d_ws, size_t ws_size,
                              hipStream_t stream)
{
    const int*   sent  = (const int*)d_in[0];
    const float* embed = (const float*)d_in[1];
    const float* WihF  = (const float*)d_in[2];
    const float* WhhF  = (const float*)d_in[3];
    const float* bihF  = (const float*)d_in[4];
    const float* bhhF  = (const float*)d_in[5];
    const float* WihB  = (const float*)d_in[6];
    const float* WhhB  = (const float*)d_in[7];
    const float* bihB  = (const float*)d_in[8];
    const float* bhhB  = (const float*)d_in[9];
    const float* h0    = (const float*)d_in[10];
    const float* c0    = (const float*)d_in[11];
    const float* Wout  = (const float*)d_in[12];
    const float* bout  = (const float*)d_in[13];
    const float* trans = (const float*)d_in[14];
    float* out = (float*)d_out;

    float* ws = (float*)d_ws;
    float* hf = ws;                                   // 4 MB
    float* hb = hf + (size_t)S_LEN * HD;              // 4 MB
    float* feats = hb + (size_t)S_LEN * HD;           // 96 KB

    // 1) sentinel-fill both h buffers (byte pattern 0x7F -> fp32 3.39e38)
    hipMemsetAsync(hf, 0x7F, (size_t)2 * S_LEN * HD * sizeof(float), stream);
    // 2) recurrence with fused X computation (no xgemm), both directions concurrently
    lstm_rec<<<128, 256, 0, stream>>>(WhhF, WhhB, WihF, WihB,
                                      bihF, bhhF, bihB, bhhB,
                                      sent, embed, h0, c0,
                                      (unsigned*)hf, (unsigned*)hb);
    // 3) emission features
    {
        int n = S_LEN * NTAG;
        feats_k<<<(n + 255)/256, 256, 0, stream>>>(hf, hb, Wout, bout, feats);
    }
    // 4) Viterbi decode
    viterbi_k<<<1, 256, 0, stream>>>(feats, trans, out);
}